// Round 1
// baseline (167.830 us; speedup 1.0000x reference)
//
#include <hip/hip_runtime.h>
#include <stdint.h>

#define NB 8
#define NC 256
#define NH 128
#define NW 128
#define NJ 8
#define NS 256
#define NHW (NH*NW)   // 16384
#define BN_EPS 1e-5f

// ---------------- K1: per-(b,c) partial sums for BN stats ----------------
__global__ __launch_bounds__(256) void k_stats(const float* __restrict__ fp,
                                               float* __restrict__ psum,
                                               float* __restrict__ psq) {
    int blk = blockIdx.x;
    int b = blk >> 8, c = blk & 255;
    const float4* p = (const float4*)(fp + (size_t)(b * NC + c) * NHW);
    float s = 0.f, q = 0.f;
    for (int i = threadIdx.x; i < NHW / 4; i += 256) {
        float4 v = p[i];
        s += v.x + v.y + v.z + v.w;
        q += v.x * v.x + v.y * v.y + v.z * v.z + v.w * v.w;
    }
    for (int o = 32; o > 0; o >>= 1) {
        s += __shfl_down(s, o);
        q += __shfl_down(q, o);
    }
    __shared__ float ls[4], lq[4];
    int wid = threadIdx.x >> 6, lane = threadIdx.x & 63;
    if (lane == 0) { ls[wid] = s; lq[wid] = q; }
    __syncthreads();
    if (threadIdx.x == 0) {
        float S2 = 0.f, Q2 = 0.f;
        for (int i = 0; i < 4; i++) { S2 += ls[i]; Q2 += lq[i]; }
        psum[c * 8 + b] = S2;
        psq[c * 8 + b] = Q2;
    }
}

// ---------------- K2: finalize BN affine params (a, b2) + conv biases ----
__global__ void k_params(const float* __restrict__ psum, const float* __restrict__ psq,
                         const float* __restrict__ bnw, const float* __restrict__ bnb,
                         const float* __restrict__ cgb, const float* __restrict__ cbb,
                         float4* __restrict__ param) {
    int c = threadIdx.x;
    float s = 0.f, q = 0.f;
    for (int b = 0; b < NB; b++) { s += psum[c * 8 + b]; q += psq[c * 8 + b]; }
    const float N = (float)(NB * NHW);
    float mean = s / N;
    float var = q / N - mean * mean;
    if (var < 0.f) var = 0.f;
    float inv = 1.0f / sqrtf(var + BN_EPS);
    float a = bnw[c] * inv;
    float b2 = bnb[c] - mean * a;
    param[c] = make_float4(a, b2, cgb[c], cbb[c]);
}

// ---------------- K3: label map from one-hot sg ----------------
__global__ __launch_bounds__(256) void k_labels(const float* __restrict__ sg,
                                                uint8_t* __restrict__ lab) {
    int pix = blockIdx.x * 256 + threadIdx.x;   // < NB*NHW
    int b = pix >> 14, hw = pix & 16383;
    const float* base = sg + (size_t)b * NJ * NHW + hw;
    int l = 0;
    #pragma unroll
    for (int j = 0; j < NJ; j++)
        if (base[(size_t)j * NHW] > 0.5f) l = j;
    lab[pix] = (uint8_t)l;
}

// ---------------- K4: mu[b,j,t] = relu(fc(codes)) ----------------
__global__ __launch_bounds__(256) void k_mu(const float* __restrict__ style, const int* __restrict__ mask,
                                            const float* __restrict__ fcw, const float* __restrict__ fcb,
                                            float* __restrict__ mu) {
    int bj = blockIdx.x;
    int b = bj >> 3, j = bj & 7;
    __shared__ float code[NS];
    int row = (mask[bj] == 1) ? j : NJ;
    const float* cp = style + ((size_t)b * (NJ + 1) + row) * NS;
    code[threadIdx.x] = cp[threadIdx.x];
    __syncthreads();
    int t = threadIdx.x;
    const float4* w4 = (const float4*)(fcw + ((size_t)j * NS + t) * NS);
    const float4* c4 = (const float4*)code;
    float acc = fcb[j * NS + t];
    for (int s4 = 0; s4 < NS / 4; s4++) {
        float4 wv = w4[s4];
        float4 cv = c4[s4];
        acc += wv.x * cv.x + wv.y * cv.y + wv.z * cv.z + wv.w * cv.w;
    }
    mu[bj * NS + t] = fmaxf(acc, 0.f);
}

// ---------------- K5: transpose conv weights [c][s][k] -> [k][s][c] ------
__global__ __launch_bounds__(256) void k_transpose(const float* __restrict__ wg, const float* __restrict__ wb,
                                                   float* __restrict__ wgt, float* __restrict__ wbt) {
    int c = blockIdx.x;
    const float* a = wg + (size_t)c * NS * 9;
    const float* d = wb + (size_t)c * NS * 9;
    for (int i = threadIdx.x; i < NS * 9; i += 256) {
        int s = i / 9, k = i - s * 9;
        wgt[((size_t)k * NS + s) * NC + c] = a[i];
        wbt[((size_t)k * NS + s) * NC + c] = d[i];
    }
}

// ---------------- K6: T[b][k][c][j] = (bf16 gamma, bf16 beta) pairs ------
__global__ __launch_bounds__(256) void k_tables(const float* __restrict__ mu, const float* __restrict__ wgt,
                                                const float* __restrict__ wbt, uint32_t* __restrict__ T) {
    int blk = blockIdx.x;
    int b = blk / 9, k = blk - b * 9;
    __shared__ float m[NJ][NS];
    for (int i = threadIdx.x; i < NJ * NS; i += 256)
        ((float*)m)[i] = mu[(size_t)b * NJ * NS + i];
    __syncthreads();
    int c = threadIdx.x;
    float ag[NJ], ab[NJ];
    #pragma unroll
    for (int j = 0; j < NJ; j++) { ag[j] = 0.f; ab[j] = 0.f; }
    const float* pg = wgt + (size_t)k * NS * NC + c;
    const float* pb = wbt + (size_t)k * NS * NC + c;
    for (int s = 0; s < NS; s++) {
        float wgv = pg[(size_t)s * NC];
        float wbv = pb[(size_t)s * NC];
        #pragma unroll
        for (int j = 0; j < NJ; j++) {
            ag[j] += m[j][s] * wgv;
            ab[j] += m[j][s] * wbv;
        }
    }
    uint32_t* o = T + (((size_t)b * 9 + k) * NC + c) * NJ;
    #pragma unroll
    for (int j = 0; j < NJ; j++) {
        uint32_t g = __float_as_uint(ag[j]);
        uint32_t bb = __float_as_uint(ab[j]);
        uint32_t gl = (g + 0x7fffu + ((g >> 16) & 1u)) >> 16;   // RN-even bf16
        uint32_t bl = (bb + 0x7fffu + ((bb >> 16) & 1u)) >> 16;
        o[j] = gl | (bl << 16);
    }
}

// ---------------- K7: fused BN + table-gather "conv" + modulation --------
__global__ __launch_bounds__(256) void k_main(const float* __restrict__ fp, const uint8_t* __restrict__ lab,
                                              const uint32_t* __restrict__ T, const float4* __restrict__ param,
                                              float* __restrict__ out) {
    int blk = blockIdx.x;
    int b = blk >> 7, h = blk & 127;
    __shared__ uint32_t Tl[9 * NC * NJ];   // 73728 B, layout [k][c][j]
    __shared__ float4 Pl[NC];              // 4096 B
    __shared__ uint8_t Ll[3][NW];          // 3 label rows

    const uint4* Tg = (const uint4*)(T + (size_t)b * 9 * NC * NJ);
    uint4* Tld = (uint4*)Tl;
    for (int i = threadIdx.x; i < 9 * NC * NJ / 4; i += 256) Tld[i] = Tg[i];
    if (threadIdx.x < NC) Pl[threadIdx.x] = param[threadIdx.x];
    if (threadIdx.x < 96) {
        int r = threadIdx.x >> 5, q = threadIdx.x & 31;
        int hr = h - 1 + r;
        uint32_t v = 0;
        if (hr >= 0 && hr < NH)
            v = ((const uint32_t*)(lab + (size_t)b * NHW + (size_t)hr * NW))[q];
        ((uint32_t*)Ll)[threadIdx.x] = v;
    }
    __syncthreads();

    int t = threadIdx.x;
    int w = t & 127;
    int cg = t >> 7;

    // hoist per-pixel neighbor labels + validity (c-independent)
    int jj[9];
    uint32_t msk[9];
    #pragma unroll
    for (int kdy = 0; kdy < 3; kdy++) {
        bool rok = (kdy == 0) ? (h - 1 >= 0) : ((kdy == 2) ? (h + 1 < NH) : true);
        #pragma unroll
        for (int kdx = 0; kdx < 3; kdx++) {
            int ww = w + (kdx - 1);
            bool ok = rok && (ww >= 0) && (ww < NW);
            int wc = ww < 0 ? 0 : (ww > NW - 1 ? NW - 1 : ww);
            int k = kdy * 3 + kdx;
            jj[k] = (int)Ll[kdy][wc];
            msk[k] = ok ? 0xffffffffu : 0u;
        }
    }

    const float* fpb = fp + (size_t)b * NC * NHW + (size_t)h * NW + w;
    float* ob = out + (size_t)b * NC * NHW + (size_t)h * NW + w;

    for (int ci = 0; ci < 128; ci++) {
        int c = ci * 2 + cg;
        float4 pa = Pl[c];
        float x = fpb[(size_t)c * NHW];
        float xn = x * pa.x + pa.y;
        float gamma = pa.z, beta = pa.w;
        #pragma unroll
        for (int k = 0; k < 9; k++) {
            uint32_t pr = Tl[(k * NC + c) * NJ + jj[k]] & msk[k];
            gamma += __uint_as_float(pr << 16);
            beta  += __uint_as_float(pr & 0xffff0000u);
        }
        ob[(size_t)c * NHW] = xn * (1.f + gamma) + beta;
    }
}

extern "C" void kernel_launch(void* const* d_in, const int* in_sizes, int n_in,
                              void* d_out, int out_size, void* d_ws, size_t ws_size,
                              hipStream_t stream) {
    const float* fp    = (const float*)d_in[0];
    const float* sg    = (const float*)d_in[1];
    const float* style = (const float*)d_in[2];
    const int*   mask  = (const int*)d_in[3];
    const float* bnw   = (const float*)d_in[4];
    const float* bnb   = (const float*)d_in[5];
    const float* cgw   = (const float*)d_in[6];
    const float* cgb   = (const float*)d_in[7];
    const float* cbw   = (const float*)d_in[8];
    const float* cbb   = (const float*)d_in[9];
    const float* fcw   = (const float*)d_in[10];
    const float* fcb   = (const float*)d_in[11];
    float* out = (float*)d_out;

    char* ws = (char*)d_ws;
    float*    psum  = (float*)(ws + 0);          //  8 KB
    float*    psq   = (float*)(ws + 8192);       //  8 KB
    float4*   param = (float4*)(ws + 16384);     //  4 KB
    uint8_t*  lab   = (uint8_t*)(ws + 20480);    // 128 KB
    float*    mu    = (float*)(ws + 151552);     //  64 KB
    float*    wgt   = (float*)(ws + 217088);     // 2.25 MB
    float*    wbt   = (float*)(ws + 2576384);    // 2.25 MB
    uint32_t* T     = (uint32_t*)(ws + 4935680); // 576 KB   (total ~5.3 MB)

    hipLaunchKernelGGL(k_stats,     dim3(NB * NC),       dim3(256), 0, stream, fp, psum, psq);
    hipLaunchKernelGGL(k_params,    dim3(1),             dim3(256), 0, stream, psum, psq, bnw, bnb, cgb, cbb, param);
    hipLaunchKernelGGL(k_labels,    dim3(NB * NHW / 256),dim3(256), 0, stream, sg, lab);
    hipLaunchKernelGGL(k_mu,        dim3(NB * NJ),       dim3(256), 0, stream, style, mask, fcw, fcb, mu);
    hipLaunchKernelGGL(k_transpose, dim3(NC),            dim3(256), 0, stream, cgw, cbw, wgt, wbt);
    hipLaunchKernelGGL(k_tables,    dim3(NB * 9),        dim3(256), 0, stream, mu, wgt, wbt, T);
    hipLaunchKernelGGL(k_main,      dim3(NB * NH),       dim3(256), 0, stream, fp, lab, T, param, out);
}

// Round 3
// 123.548 us; speedup vs baseline: 1.3584x; 1.3584x over previous
//
#include <hip/hip_runtime.h>
#include <hip/hip_fp16.h>
#include <stdint.h>

#define NB 8
#define NC 256
#define NH 128
#define NW 128
#define NJ 8
#define NS 256
#define NHW (NH*NW)   // 16384
#define BN_EPS 1e-5f
#define TSTRIDE 68    // u32 stride per (k,j) row in LDS: 16B-aligned, 4j%32 banks

__device__ inline __half2 u2h(uint32_t u) {
    union { uint32_t u; __half2 h; } x; x.u = u; return x.h;
}
__device__ inline uint32_t h2u(__half2 h) {
    union { uint32_t u; __half2 h; } x; x.h = h; return x.u;
}

// ---------------- K1: per-(b,c) partial sums for BN stats ----------------
__global__ __launch_bounds__(256) void k_stats(const float* __restrict__ fp,
                                               float* __restrict__ psum,
                                               float* __restrict__ psq) {
    int blk = blockIdx.x;
    int b = blk >> 8, c = blk & 255;
    const float4* p = (const float4*)(fp + (size_t)(b * NC + c) * NHW);
    float s = 0.f, q = 0.f;
    for (int i = threadIdx.x; i < NHW / 4; i += 256) {
        float4 v = p[i];
        s += v.x + v.y + v.z + v.w;
        q += v.x * v.x + v.y * v.y + v.z * v.z + v.w * v.w;
    }
    for (int o = 32; o > 0; o >>= 1) {
        s += __shfl_down(s, o);
        q += __shfl_down(q, o);
    }
    __shared__ float ls[4], lq[4];
    int wid = threadIdx.x >> 6, lane = threadIdx.x & 63;
    if (lane == 0) { ls[wid] = s; lq[wid] = q; }
    __syncthreads();
    if (threadIdx.x == 0) {
        float S2 = 0.f, Q2 = 0.f;
        for (int i = 0; i < 4; i++) { S2 += ls[i]; Q2 += lq[i]; }
        psum[c * 8 + b] = S2;
        psq[c * 8 + b] = Q2;
    }
}

// ---------------- K2 (fused prep): labels | mu | weight transpose --------
__global__ __launch_bounds__(256) void k_prep(
        const float* __restrict__ sg, uint8_t* __restrict__ lab,
        const float* __restrict__ style, const int* __restrict__ mask,
        const float* __restrict__ fcw, const float* __restrict__ fcb,
        float* __restrict__ mu,
        const float* __restrict__ wg, const float* __restrict__ wb,
        float* __restrict__ wgt, float* __restrict__ wbt) {
    __shared__ float code[NS];
    int blk = blockIdx.x;
    int t = threadIdx.x;
    if (blk < 512) {
        // labels: one-hot argmax
        int pix = blk * 256 + t;
        int b = pix >> 14, hw = pix & 16383;
        const float* base = sg + (size_t)b * NJ * NHW + hw;
        int l = 0;
        #pragma unroll
        for (int j = 0; j < NJ; j++)
            if (base[(size_t)j * NHW] > 0.5f) l = j;
        lab[pix] = (uint8_t)l;
    } else if (blk < 576) {
        // mu[b,j,t] = relu(fc_j(code))
        int bj = blk - 512;
        int b = bj >> 3, j = bj & 7;
        int row = (mask[bj] == 1) ? j : NJ;
        code[t] = style[((size_t)b * (NJ + 1) + row) * NS + t];
        __syncthreads();
        const float4* w4 = (const float4*)(fcw + ((size_t)j * NS + t) * NS);
        const float4* c4 = (const float4*)code;
        float acc = fcb[j * NS + t];
        for (int s4 = 0; s4 < NS / 4; s4++) {
            float4 wv = w4[s4];
            float4 cv = c4[s4];
            acc += wv.x * cv.x + wv.y * cv.y + wv.z * cv.z + wv.w * cv.w;
        }
        mu[bj * NS + t] = fmaxf(acc, 0.f);
    } else {
        // transpose conv weights [c][s][k] -> [k][s][c]
        int c = blk - 576;
        const float* a = wg + (size_t)c * NS * 9;
        const float* d = wb + (size_t)c * NS * 9;
        for (int i = t; i < NS * 9; i += 256) {
            int s = i / 9, k = i - s * 9;
            wgt[((size_t)k * NS + s) * NC + c] = a[i];
            wbt[((size_t)k * NS + s) * NC + c] = d[i];
        }
    }
}

// ---------------- K3: finalize BN params + packed conv biases ------------
__global__ void k_params(const float* __restrict__ psum, const float* __restrict__ psq,
                         const float* __restrict__ bnw, const float* __restrict__ bnb,
                         const float* __restrict__ cgb, const float* __restrict__ cbb,
                         float2* __restrict__ Al, uint32_t* __restrict__ Bl) {
    int c = threadIdx.x;
    float s = 0.f, q = 0.f;
    for (int b = 0; b < NB; b++) { s += psum[c * 8 + b]; q += psq[c * 8 + b]; }
    const float N = (float)(NB * NHW);
    float mean = s / N;
    float var = q / N - mean * mean;
    if (var < 0.f) var = 0.f;
    float inv = 1.0f / sqrtf(var + BN_EPS);
    float a = bnw[c] * inv;
    float b2 = bnb[c] - mean * a;
    Al[c] = make_float2(a, b2);
    Bl[c] = h2u(__floats2half2_rn(1.0f + cgb[c], cbb[c]));  // (G0, B0)
}

// ---------------- K4: T[b][k][j(9)][c] = f16-packed (gamma, beta) --------
__global__ __launch_bounds__(256) void k_tables(const float* __restrict__ mu, const float* __restrict__ wgt,
                                                const float* __restrict__ wbt, uint32_t* __restrict__ T) {
    int blk = blockIdx.x;
    int b = blk / 9, k = blk - b * 9;
    __shared__ float m[NJ][NS];
    for (int i = threadIdx.x; i < NJ * NS; i += 256)
        ((float*)m)[i] = mu[(size_t)b * NJ * NS + i];
    __syncthreads();
    int c = threadIdx.x;
    float ag[NJ], ab[NJ];
    #pragma unroll
    for (int j = 0; j < NJ; j++) { ag[j] = 0.f; ab[j] = 0.f; }
    const float* pg = wgt + (size_t)k * NS * NC + c;
    const float* pb = wbt + (size_t)k * NS * NC + c;
    for (int s = 0; s < NS; s++) {
        float wgv = pg[(size_t)s * NC];
        float wbv = pb[(size_t)s * NC];
        #pragma unroll
        for (int j = 0; j < NJ; j++) {
            ag[j] += m[j][s] * wgv;
            ab[j] += m[j][s] * wbv;
        }
    }
    uint32_t* o = T + ((size_t)b * 9 + k) * 9 * NC + c;
    #pragma unroll
    for (int j = 0; j < NJ; j++)
        o[(size_t)j * NC] = h2u(__floats2half2_rn(ag[j], ab[j]));
    o[(size_t)8 * NC] = 0u;   // j=8: zero row for out-of-bounds neighbors
}

// ---------------- K5: fused BN + table-gather "conv" + modulation --------
// grid: b(8) x h(128) x cchunk(4, 64 channels each); 256 thr = 128 w x 2 cg
__global__ __launch_bounds__(256, 5) void k_main(
        const float* __restrict__ fp, const uint8_t* __restrict__ lab,
        const uint32_t* __restrict__ T, const float2* __restrict__ Ag,
        const uint32_t* __restrict__ Bg, float* __restrict__ out) {
    int blk = blockIdx.x;
    int cc = blk & 3;
    int h  = (blk >> 2) & 127;
    int b  = blk >> 9;
    int c0 = cc * 64;

    __shared__ uint32_t Tl[81 * TSTRIDE];   // 22032 B
    __shared__ float2   Apl[64];            //   512 B  (a, b2) f32
    __shared__ uint32_t Bpl[64];            //   256 B  f16-packed (1+cgb, cbb)
    __shared__ uint8_t  Ll[3][NW];          //   384 B

    int t = threadIdx.x;
    // stage T chunk: 81 rows x 64 u32, stride 68 in LDS
    {
        const uint32_t* Tg = T + (size_t)b * 81 * NC + c0;
        int idx = t & 63;
        for (int r = t >> 6; r < 81; r += 4)
            Tl[r * TSTRIDE + idx] = Tg[(size_t)r * NC + idx];
    }
    if (t < 64) { Apl[t] = Ag[c0 + t]; Bpl[t] = Bg[c0 + t]; }
    if (t < 96) {
        int r = t >> 5, q = t & 31;
        int hr = h - 1 + r;
        uint32_t v = 0;
        if (hr >= 0 && hr < NH)
            v = ((const uint32_t*)(lab + (size_t)b * NHW + (size_t)hr * NW))[q];
        ((uint32_t*)Ll)[t] = v;
    }
    __syncthreads();

    int w = t & 127, cg = t >> 7;
    // per-pixel neighbor labels; 8 = OOB (zero row)
    int base_k[9];
    #pragma unroll
    for (int dy = 0; dy < 3; dy++) {
        int hr = h - 1 + dy;
        bool rok = (hr >= 0) && (hr < NH);
        #pragma unroll
        for (int dx = 0; dx < 3; dx++) {
            int ww = w - 1 + dx;
            bool ok = rok && (ww >= 0) && (ww < NW);
            int wc = ww < 0 ? 0 : (ww > NW - 1 ? NW - 1 : ww);
            int j = ok ? (int)Ll[dy][wc] : 8;
            int k = dy * 3 + dx;
            base_k[k] = (k * 9 + j) * TSTRIDE + cg * 32;
        }
    }

    const float* fpb = fp + ((size_t)b * NC + c0 + cg * 32) * NHW + (size_t)h * NW + w;
    float*       ob  = out + ((size_t)b * NC + c0 + cg * 32) * NHW + (size_t)h * NW + w;

    #pragma unroll
    for (int q = 0; q < 8; q++) {
        uint4 bias = *(const uint4*)&Bpl[cg * 32 + q * 4];
        __half2 a0 = u2h(bias.x), a1 = u2h(bias.y), a2 = u2h(bias.z), a3 = u2h(bias.w);
        #pragma unroll
        for (int k = 0; k < 9; k++) {
            uint4 tv = *(const uint4*)&Tl[base_k[k] + q * 4];
            a0 = __hadd2(a0, u2h(tv.x));
            a1 = __hadd2(a1, u2h(tv.y));
            a2 = __hadd2(a2, u2h(tv.z));
            a3 = __hadd2(a3, u2h(tv.w));
        }
        float4 ap01 = *(const float4*)&Apl[cg * 32 + q * 4];
        float4 ap23 = *(const float4*)&Apl[cg * 32 + q * 4 + 2];
        float x0 = fpb[(size_t)(q * 4 + 0) * NHW];
        float x1 = fpb[(size_t)(q * 4 + 1) * NHW];
        float x2 = fpb[(size_t)(q * 4 + 2) * NHW];
        float x3 = fpb[(size_t)(q * 4 + 3) * NHW];
        float2 g0 = __half22float2(a0);
        float2 g1 = __half22float2(a1);
        float2 g2 = __half22float2(a2);
        float2 g3 = __half22float2(a3);
        ob[(size_t)(q * 4 + 0) * NHW] = (x0 * ap01.x + ap01.y) * g0.x + g0.y;
        ob[(size_t)(q * 4 + 1) * NHW] = (x1 * ap01.z + ap01.w) * g1.x + g1.y;
        ob[(size_t)(q * 4 + 2) * NHW] = (x2 * ap23.x + ap23.y) * g2.x + g2.y;
        ob[(size_t)(q * 4 + 3) * NHW] = (x3 * ap23.z + ap23.w) * g3.x + g3.y;
    }
}

extern "C" void kernel_launch(void* const* d_in, const int* in_sizes, int n_in,
                              void* d_out, int out_size, void* d_ws, size_t ws_size,
                              hipStream_t stream) {
    const float* fp    = (const float*)d_in[0];
    const float* sg    = (const float*)d_in[1];
    const float* style = (const float*)d_in[2];
    const int*   mask  = (const int*)d_in[3];
    const float* bnw   = (const float*)d_in[4];
    const float* bnb   = (const float*)d_in[5];
    const float* cgw   = (const float*)d_in[6];
    const float* cgb   = (const float*)d_in[7];
    const float* cbw   = (const float*)d_in[8];
    const float* cbb   = (const float*)d_in[9];
    const float* fcw   = (const float*)d_in[10];
    const float* fcb   = (const float*)d_in[11];
    float* out = (float*)d_out;

    char* ws = (char*)d_ws;
    float*    psum = (float*)(ws + 0);           //   8 KB
    float*    psq  = (float*)(ws + 8192);        //   8 KB
    float2*   Al   = (float2*)(ws + 16384);      //   2 KB
    uint32_t* Bl   = (uint32_t*)(ws + 18432);    //   1 KB
    uint8_t*  lab  = (uint8_t*)(ws + 19456);     // 128 KB
    float*    mu   = (float*)(ws + 150528);      //  64 KB
    float*    wgt  = (float*)(ws + 216064);      // 2.25 MB
    float*    wbt  = (float*)(ws + 2575360);     // 2.25 MB
    uint32_t* T    = (uint32_t*)(ws + 4934656);  // 648 KB  (total ~5.6 MB)

    hipLaunchKernelGGL(k_stats,  dim3(NB * NC),        dim3(256), 0, stream, fp, psum, psq);
    hipLaunchKernelGGL(k_prep,   dim3(512 + 64 + 256), dim3(256), 0, stream,
                       sg, lab, style, mask, fcw, fcb, mu, cgw, cbw, wgt, wbt);
    hipLaunchKernelGGL(k_params, dim3(1),              dim3(256), 0, stream,
                       psum, psq, bnw, bnb, cgb, cbb, Al, Bl);
    hipLaunchKernelGGL(k_tables, dim3(NB * 9),         dim3(256), 0, stream, mu, wgt, wbt, T);
    hipLaunchKernelGGL(k_main,   dim3(NB * NH * 4),    dim3(256), 0, stream,
                       fp, lab, T, Al, Bl, out);
}

// Round 4
// 104.034 us; speedup vs baseline: 1.6132x; 1.1876x over previous
//
#include <hip/hip_runtime.h>
#include <hip/hip_fp16.h>
#include <stdint.h>

#define NB 8
#define NC 256
#define NH 128
#define NW 128
#define NJ 8
#define NS 256
#define NHW (NH*NW)   // 16384
#define BN_EPS 1e-5f
#define TSTRIDE 68    // u32 stride per (k,j) row in LDS: 16B-aligned, 4j%32 banks

__device__ inline __half2 u2h(uint32_t u) {
    union { uint32_t u; __half2 h; } x; x.u = u; return x.h;
}
__device__ inline uint32_t h2u(__half2 h) {
    union { uint32_t u; __half2 h; } x; x.h = h; return x.u;
}

// ============ Kernel A: stats | labels | mu | tiled transpose ============
// blocks [0,2048): BN partial sums   (b = blk>>8, c = blk&255)
// blocks [2048,2560): label map      (512 blocks)
// blocks [2560,2624): mu             (64 blocks = b*8+j)
// blocks [2624,3200): weight transpose, LDS-tiled, both sides coalesced
__global__ __launch_bounds__(256) void kA(
        const float* __restrict__ fp, float* __restrict__ psum, float* __restrict__ psq,
        const float* __restrict__ sg, uint8_t* __restrict__ lab,
        const float* __restrict__ style, const int* __restrict__ mask,
        const float* __restrict__ fcw, const float* __restrict__ fcb,
        float* __restrict__ mu,
        const float* __restrict__ wg, const float* __restrict__ wb,
        float* __restrict__ wgt, float* __restrict__ wbt) {
    __shared__ float ls[4], lq[4];
    __shared__ float code[NS];
    __shared__ float tile[32][65];
    int blk = blockIdx.x;
    int t = threadIdx.x;
    if (blk < 2048) {
        // ---- BN stats over one (b,c) plane ----
        int b = blk >> 8, c = blk & 255;
        const float4* p = (const float4*)(fp + (size_t)(b * NC + c) * NHW);
        float s = 0.f, q = 0.f;
        for (int i = t; i < NHW / 4; i += 256) {
            float4 v = p[i];
            s += v.x + v.y + v.z + v.w;
            q += v.x * v.x + v.y * v.y + v.z * v.z + v.w * v.w;
        }
        for (int o = 32; o > 0; o >>= 1) {
            s += __shfl_down(s, o);
            q += __shfl_down(q, o);
        }
        int wid = t >> 6, lane = t & 63;
        if (lane == 0) { ls[wid] = s; lq[wid] = q; }
        __syncthreads();
        if (t == 0) {
            float S2 = 0.f, Q2 = 0.f;
            for (int i = 0; i < 4; i++) { S2 += ls[i]; Q2 += lq[i]; }
            psum[c * 8 + b] = S2;
            psq[c * 8 + b] = Q2;
        }
    } else if (blk < 2560) {
        // ---- labels: one-hot argmax ----
        int pix = (blk - 2048) * 256 + t;
        int b = pix >> 14, hw = pix & 16383;
        const float* base = sg + (size_t)b * NJ * NHW + hw;
        int l = 0;
        #pragma unroll
        for (int j = 0; j < NJ; j++)
            if (base[(size_t)j * NHW] > 0.5f) l = j;
        lab[pix] = (uint8_t)l;
    } else if (blk < 2624) {
        // ---- mu[b,j,t] = relu(fc_j(code)) ----
        int bj = blk - 2560;
        int b = bj >> 3, j = bj & 7;
        int row = (mask[bj] == 1) ? j : NJ;
        code[t] = style[((size_t)b * (NJ + 1) + row) * NS + t];
        __syncthreads();
        const float4* w4 = (const float4*)(fcw + ((size_t)j * NS + t) * NS);
        const float4* c4 = (const float4*)code;
        float acc = fcb[j * NS + t];
        for (int s4 = 0; s4 < NS / 4; s4++) {
            float4 wv = w4[s4];
            float4 cv = c4[s4];
            acc += wv.x * cv.x + wv.y * cv.y + wv.z * cv.z + wv.w * cv.w;
        }
        mu[bj * NS + t] = fmaxf(acc, 0.f);
    } else {
        // ---- tiled transpose [c][sk] -> [k][s][c], sk = s*9+k in [0,2304) ----
        int i = blk - 2624;                    // 576 blocks
        int tb = i / 288, r = i - tb * 288;    // table, then tile
        int skc = r % 72, cc = r / 72;
        int sk0 = skc * 32, c0 = cc * 64;
        const float* src = tb ? wb : wg;
        float* dst = tb ? wbt : wgt;
        {
            int skl = t & 31, cl = t >> 5;     // 8 c per pass
            #pragma unroll
            for (int p = 0; p < 8; p++)
                tile[skl][cl + p * 8] = src[(size_t)(c0 + cl + p * 8) * 2304 + sk0 + skl];
        }
        __syncthreads();
        {
            int cl = t & 63, skl = t >> 6;     // 4 sk per pass
            #pragma unroll
            for (int p = 0; p < 8; p++) {
                int sk = sk0 + skl + p * 4;
                int s = sk / 9, k = sk - s * 9;
                dst[(size_t)k * (NS * NC) + (size_t)s * NC + c0 + cl] = tile[skl + p * 4][cl];
            }
        }
    }
}

// ============ Kernel B: params (blk 0) | tables (blk 1..72) ============
__global__ __launch_bounds__(256) void kB(
        const float* __restrict__ psum, const float* __restrict__ psq,
        const float* __restrict__ bnw, const float* __restrict__ bnb,
        const float* __restrict__ cgb, const float* __restrict__ cbb,
        float2* __restrict__ Al, uint32_t* __restrict__ Bl,
        const float* __restrict__ mu, const float* __restrict__ wgt,
        const float* __restrict__ wbt, uint32_t* __restrict__ T) {
    int blk = blockIdx.x;
    int t = threadIdx.x;
    if (blk == 0) {
        int c = t;
        float s = 0.f, q = 0.f;
        for (int b = 0; b < NB; b++) { s += psum[c * 8 + b]; q += psq[c * 8 + b]; }
        const float N = (float)(NB * NHW);
        float mean = s / N;
        float var = q / N - mean * mean;
        if (var < 0.f) var = 0.f;
        float inv = 1.0f / sqrtf(var + BN_EPS);
        float a = bnw[c] * inv;
        float b2 = bnb[c] - mean * a;
        Al[c] = make_float2(a, b2);
        Bl[c] = h2u(__floats2half2_rn(1.0f + cgb[c], cbb[c]));  // (G0, B0)
        return;
    }
    int bk = blk - 1;
    int b = bk / 9, k = bk - b * 9;
    __shared__ float m[NJ][NS];
    for (int i = t; i < NJ * NS; i += 256)
        ((float*)m)[i] = mu[(size_t)b * NJ * NS + i];
    __syncthreads();
    int c = t;
    float ag[NJ], ab[NJ];
    #pragma unroll
    for (int j = 0; j < NJ; j++) { ag[j] = 0.f; ab[j] = 0.f; }
    const float* pg = wgt + (size_t)k * NS * NC + c;
    const float* pb = wbt + (size_t)k * NS * NC + c;
    for (int s = 0; s < NS; s++) {
        float wgv = pg[(size_t)s * NC];
        float wbv = pb[(size_t)s * NC];
        #pragma unroll
        for (int j = 0; j < NJ; j++) {
            ag[j] += m[j][s] * wgv;
            ab[j] += m[j][s] * wbv;
        }
    }
    uint32_t* o = T + ((size_t)b * 9 + k) * 9 * NC + c;
    #pragma unroll
    for (int j = 0; j < NJ; j++)
        o[(size_t)j * NC] = h2u(__floats2half2_rn(ag[j], ab[j]));
    o[(size_t)8 * NC] = 0u;   // j=8: zero row for out-of-bounds neighbors
}

// ============ Kernel C: fused BN + table-gather "conv" + modulation ======
// grid: b(8) x h(128) x cchunk(4, 64 channels each); 256 thr = 128 w x 2 cg
__global__ __launch_bounds__(256, 5) void k_main(
        const float* __restrict__ fp, const uint8_t* __restrict__ lab,
        const uint32_t* __restrict__ T, const float2* __restrict__ Ag,
        const uint32_t* __restrict__ Bg, float* __restrict__ out) {
    int blk = blockIdx.x;
    int cc = blk & 3;
    int h  = (blk >> 2) & 127;
    int b  = blk >> 9;
    int c0 = cc * 64;

    __shared__ uint32_t Tl[81 * TSTRIDE];   // 22032 B
    __shared__ float2   Apl[64];            //   512 B  (a, b2) f32
    __shared__ uint32_t Bpl[64];            //   256 B  f16-packed (1+cgb, cbb)
    __shared__ uint8_t  Ll[3][NW];          //   384 B

    int t = threadIdx.x;
    // stage T chunk: 81 rows x 64 u32 (uint4 loads), stride 68 in LDS
    {
        const uint32_t* Tg = T + (size_t)b * 81 * NC + c0;
        int rr = t >> 4, ii = (t & 15) * 4;
        #pragma unroll
        for (int pass = 0; pass < 5; pass++) {
            int r = rr + pass * 16;
            *(uint4*)&Tl[r * TSTRIDE + ii] = *(const uint4*)&Tg[(size_t)r * NC + ii];
        }
        if (t < 16) *(uint4*)&Tl[80 * TSTRIDE + t * 4] = *(const uint4*)&Tg[(size_t)80 * NC + t * 4];
    }
    if (t < 64) { Apl[t] = Ag[c0 + t]; Bpl[t] = Bg[c0 + t]; }
    if (t >= 128 && t < 224) {
        int tt = t - 128;
        int r = tt >> 5, q = tt & 31;
        int hr = h - 1 + r;
        uint32_t v = 0;
        if (hr >= 0 && hr < NH)
            v = ((const uint32_t*)(lab + (size_t)b * NHW + (size_t)hr * NW))[q];
        ((uint32_t*)Ll)[tt] = v;
    }
    __syncthreads();

    int w = t & 127, cg = t >> 7;
    // per-pixel neighbor labels; 8 = OOB (zero row)
    int base_k[9];
    #pragma unroll
    for (int dy = 0; dy < 3; dy++) {
        int hr = h - 1 + dy;
        bool rok = (hr >= 0) && (hr < NH);
        #pragma unroll
        for (int dx = 0; dx < 3; dx++) {
            int ww = w - 1 + dx;
            bool ok = rok && (ww >= 0) && (ww < NW);
            int wc = ww < 0 ? 0 : (ww > NW - 1 ? NW - 1 : ww);
            int j = ok ? (int)Ll[dy][wc] : 8;
            int k = dy * 3 + dx;
            base_k[k] = (k * 9 + j) * TSTRIDE + cg * 32;
        }
    }

    const float* fpb = fp + ((size_t)b * NC + c0 + cg * 32) * NHW + (size_t)h * NW + w;
    float*       ob  = out + ((size_t)b * NC + c0 + cg * 32) * NHW + (size_t)h * NW + w;

    #pragma unroll
    for (int q = 0; q < 8; q++) {
        uint4 bias = *(const uint4*)&Bpl[cg * 32 + q * 4];
        __half2 a0 = u2h(bias.x), a1 = u2h(bias.y), a2 = u2h(bias.z), a3 = u2h(bias.w);
        #pragma unroll
        for (int k = 0; k < 9; k++) {
            uint4 tv = *(const uint4*)&Tl[base_k[k] + q * 4];
            a0 = __hadd2(a0, u2h(tv.x));
            a1 = __hadd2(a1, u2h(tv.y));
            a2 = __hadd2(a2, u2h(tv.z));
            a3 = __hadd2(a3, u2h(tv.w));
        }
        float4 ap01 = *(const float4*)&Apl[cg * 32 + q * 4];
        float4 ap23 = *(const float4*)&Apl[cg * 32 + q * 4 + 2];
        float x0 = fpb[(size_t)(q * 4 + 0) * NHW];
        float x1 = fpb[(size_t)(q * 4 + 1) * NHW];
        float x2 = fpb[(size_t)(q * 4 + 2) * NHW];
        float x3 = fpb[(size_t)(q * 4 + 3) * NHW];
        float2 g0 = __half22float2(a0);
        float2 g1 = __half22float2(a1);
        float2 g2 = __half22float2(a2);
        float2 g3 = __half22float2(a3);
        // non-temporal: don't let `out` write-allocate L3 and evict fp
        __builtin_nontemporal_store((x0 * ap01.x + ap01.y) * g0.x + g0.y, &ob[(size_t)(q * 4 + 0) * NHW]);
        __builtin_nontemporal_store((x1 * ap01.z + ap01.w) * g1.x + g1.y, &ob[(size_t)(q * 4 + 1) * NHW]);
        __builtin_nontemporal_store((x2 * ap23.x + ap23.y) * g2.x + g2.y, &ob[(size_t)(q * 4 + 2) * NHW]);
        __builtin_nontemporal_store((x3 * ap23.z + ap23.w) * g3.x + g3.y, &ob[(size_t)(q * 4 + 3) * NHW]);
    }
}

extern "C" void kernel_launch(void* const* d_in, const int* in_sizes, int n_in,
                              void* d_out, int out_size, void* d_ws, size_t ws_size,
                              hipStream_t stream) {
    const float* fp    = (const float*)d_in[0];
    const float* sg    = (const float*)d_in[1];
    const float* style = (const float*)d_in[2];
    const int*   mask  = (const int*)d_in[3];
    const float* bnw   = (const float*)d_in[4];
    const float* bnb   = (const float*)d_in[5];
    const float* cgw   = (const float*)d_in[6];
    const float* cgb   = (const float*)d_in[7];
    const float* cbw   = (const float*)d_in[8];
    const float* cbb   = (const float*)d_in[9];
    const float* fcw   = (const float*)d_in[10];
    const float* fcb   = (const float*)d_in[11];
    float* out = (float*)d_out;

    char* ws = (char*)d_ws;
    float*    psum = (float*)(ws + 0);           //   8 KB
    float*    psq  = (float*)(ws + 8192);        //   8 KB
    float2*   Al   = (float2*)(ws + 16384);      //   2 KB
    uint32_t* Bl   = (uint32_t*)(ws + 18432);    //   1 KB
    uint8_t*  lab  = (uint8_t*)(ws + 19456);     // 128 KB
    float*    mu   = (float*)(ws + 150528);      //  64 KB
    float*    wgt  = (float*)(ws + 216064);      // 2.25 MB
    float*    wbt  = (float*)(ws + 2575360);     // 2.25 MB
    uint32_t* T    = (uint32_t*)(ws + 4934656);  // 648 KB  (total ~5.6 MB)

    hipLaunchKernelGGL(kA, dim3(3200), dim3(256), 0, stream,
                       fp, psum, psq, sg, lab, style, mask, fcw, fcb, mu,
                       cgw, cbw, wgt, wbt);
    hipLaunchKernelGGL(kB, dim3(73), dim3(256), 0, stream,
                       psum, psq, bnw, bnb, cgb, cbb, Al, Bl, mu, wgt, wbt, T);
    hipLaunchKernelGGL(k_main, dim3(NB * NH * 4), dim3(256), 0, stream,
                       fp, lab, T, Al, Bl, out);
}

// Round 5
// 90.537 us; speedup vs baseline: 1.8537x; 1.1491x over previous
//
#include <hip/hip_runtime.h>
#include <hip/hip_fp16.h>
#include <stdint.h>

#define NB 8
#define NC 256
#define NH 128
#define NW 128
#define NJ 8
#define NS 256
#define NHW (NH*NW)   // 16384
#define BN_EPS 1e-5f
#define TSTRIDE 68    // u32 stride per (k,j) row in LDS: 16B-aligned, 4j%32 banks

__device__ inline __half2 u2h(uint32_t u) {
    union { uint32_t u; __half2 h; } x; x.u = u; return x.h;
}
__device__ inline uint32_t h2u(__half2 h) {
    union { uint32_t u; __half2 h; } x; x.h = h; return x.u;
}

// ============ Kernel A: stats | labels | mu | transpose+pack ============
// blocks [0,2048): BN partial sums   (b = blk>>8, c = blk&255)
// blocks [2048,2560): label map      (512 blocks)
// blocks [2560,2624): mu             (64 blocks = b*8+j)
// blocks [2624,2912): weight transpose+f16-pack, both sides coalesced
__global__ __launch_bounds__(256) void kA(
        const float* __restrict__ fp, float* __restrict__ psum, float* __restrict__ psq,
        const float* __restrict__ sg, uint8_t* __restrict__ lab,
        const float* __restrict__ style, const int* __restrict__ mask,
        const float* __restrict__ fcw, const float* __restrict__ fcb,
        float* __restrict__ mu,
        const float* __restrict__ wg, const float* __restrict__ wb,
        uint32_t* __restrict__ wpk) {
    __shared__ float ls[4], lq[4];
    __shared__ float code[NS];
    __shared__ uint32_t tileu[32][65];
    int blk = blockIdx.x;
    int t = threadIdx.x;
    if (blk < 2048) {
        // ---- BN stats over one (b,c) plane ----
        int b = blk >> 8, c = blk & 255;
        const float4* p = (const float4*)(fp + (size_t)(b * NC + c) * NHW);
        float s = 0.f, q = 0.f;
        for (int i = t; i < NHW / 4; i += 256) {
            float4 v = p[i];
            s += v.x + v.y + v.z + v.w;
            q += v.x * v.x + v.y * v.y + v.z * v.z + v.w * v.w;
        }
        for (int o = 32; o > 0; o >>= 1) {
            s += __shfl_down(s, o);
            q += __shfl_down(q, o);
        }
        int wid = t >> 6, lane = t & 63;
        if (lane == 0) { ls[wid] = s; lq[wid] = q; }
        __syncthreads();
        if (t == 0) {
            float S2 = 0.f, Q2 = 0.f;
            for (int i = 0; i < 4; i++) { S2 += ls[i]; Q2 += lq[i]; }
            psum[c * 8 + b] = S2;
            psq[c * 8 + b] = Q2;
        }
    } else if (blk < 2560) {
        // ---- labels: one-hot argmax ----
        int pix = (blk - 2048) * 256 + t;
        int b = pix >> 14, hw = pix & 16383;
        const float* base = sg + (size_t)b * NJ * NHW + hw;
        int l = 0;
        #pragma unroll
        for (int j = 0; j < NJ; j++)
            if (base[(size_t)j * NHW] > 0.5f) l = j;
        lab[pix] = (uint8_t)l;
    } else if (blk < 2624) {
        // ---- mu[b,j,t] = relu(fc_j(code)) ----
        int bj = blk - 2560;
        int b = bj >> 3, j = bj & 7;
        int row = (mask[bj] == 1) ? j : NJ;
        code[t] = style[((size_t)b * (NJ + 1) + row) * NS + t];
        __syncthreads();
        const float4* w4 = (const float4*)(fcw + ((size_t)j * NS + t) * NS);
        const float4* c4 = (const float4*)code;
        float acc = fcb[j * NS + t];
        for (int s4 = 0; s4 < NS / 4; s4++) {
            float4 wv = w4[s4];
            float4 cv = c4[s4];
            acc += wv.x * cv.x + wv.y * cv.y + wv.z * cv.z + wv.w * cv.w;
        }
        mu[bj * NS + t] = fmaxf(acc, 0.f);
    } else {
        // ---- transpose+pack [c][sk]x2 -> wpk[k][s][c] u32(h2: wg,wb) ----
        int i = blk - 2624;                    // 0..287
        int skc = i % 72, cc = i / 72;
        int sk0 = skc * 32, c0 = cc * 64;
        {
            int skl = t & 31, cl = t >> 5;     // 8 c per pass
            #pragma unroll
            for (int p = 0; p < 8; p++) {
                int c = c0 + cl + p * 8;
                float g  = __builtin_nontemporal_load(&wg[(size_t)c * 2304 + sk0 + skl]);
                float b2 = __builtin_nontemporal_load(&wb[(size_t)c * 2304 + sk0 + skl]);
                tileu[skl][cl + p * 8] = h2u(__floats2half2_rn(g, b2));
            }
        }
        __syncthreads();
        {
            int cl = t & 63, skl = t >> 6;     // 4 sk per pass
            #pragma unroll
            for (int p = 0; p < 8; p++) {
                int sk = sk0 + skl + p * 4;
                int s = sk / 9, k = sk - s * 9;
                wpk[(size_t)k * (NS * NC) + (size_t)s * NC + c0 + cl] = tileu[skl + p * 4][cl];
            }
        }
    }
}

// ============ Kernel B: tables (blk 0..71) | params (blk 72) ============
// tables: 1024 thr = 256 c x 4 j-pairs; mu staged [s][j] in LDS
__global__ __launch_bounds__(1024) void kB(
        const float* __restrict__ psum, const float* __restrict__ psq,
        const float* __restrict__ bnw, const float* __restrict__ bnb,
        const float* __restrict__ cgb, const float* __restrict__ cbb,
        float2* __restrict__ Al, uint32_t* __restrict__ Bl,
        const float* __restrict__ mu, const uint32_t* __restrict__ wpk,
        uint32_t* __restrict__ T) {
    int blk = blockIdx.x;
    int t = threadIdx.x;
    if (blk == 72) {
        if (t < 256) {
            int c = t;
            float s = 0.f, q = 0.f;
            for (int b = 0; b < NB; b++) { s += psum[c * 8 + b]; q += psq[c * 8 + b]; }
            const float N = (float)(NB * NHW);
            float mean = s / N;
            float var = q / N - mean * mean;
            if (var < 0.f) var = 0.f;
            float inv = 1.0f / sqrtf(var + BN_EPS);
            float a = bnw[c] * inv;
            float b2 = bnb[c] - mean * a;
            Al[c] = make_float2(a, b2);
            Bl[c] = h2u(__floats2half2_rn(1.0f + cgb[c], cbb[c]));  // (G0, B0)
        }
        return;
    }
    int b = blk / 9, k = blk - b * 9;
    __shared__ float ms[NS * NJ];   // [s][j] layout
    for (int i = t; i < NJ * NS; i += 1024) {
        int j = i >> 8, s = i & 255;
        ms[s * 8 + j] = mu[(size_t)b * NJ * NS + i];
    }
    __syncthreads();
    int c = t & 255, jq = t >> 8;
    int j0 = jq * 2;
    const uint32_t* wp = wpk + (size_t)k * NS * NC + c;
    float g0 = 0.f, be0 = 0.f, g1 = 0.f, be1 = 0.f;
    for (int s = 0; s < NS; s++) {
        float2 w2 = __half22float2(u2h(wp[(size_t)s * NC]));
        float2 mm = *(const float2*)&ms[s * 8 + j0];
        g0  += mm.x * w2.x;  be0 += mm.x * w2.y;
        g1  += mm.y * w2.x;  be1 += mm.y * w2.y;
    }
    uint32_t* o = T + ((size_t)b * 9 + k) * 9 * NC + c;
    o[(size_t)j0 * NC]       = h2u(__floats2half2_rn(g0, be0));
    o[(size_t)(j0 + 1) * NC] = h2u(__floats2half2_rn(g1, be1));
    if (jq == 0) o[(size_t)8 * NC] = 0u;   // zero row for OOB neighbors
}

// ============ Kernel C: fused BN + table-gather "conv" + modulation ======
// grid: b(8) x h(128) x cchunk(4, 64 channels each); 256 thr = 128 w x 2 cg
__global__ __launch_bounds__(256, 5) void k_main(
        const float* __restrict__ fp, const uint8_t* __restrict__ lab,
        const uint32_t* __restrict__ T, const float2* __restrict__ Ag,
        const uint32_t* __restrict__ Bg, float* __restrict__ out) {
    int blk = blockIdx.x;
    int cc = blk & 3;
    int h  = (blk >> 2) & 127;
    int b  = blk >> 9;
    int c0 = cc * 64;

    __shared__ uint32_t Tl[81 * TSTRIDE];   // 22032 B
    __shared__ float2   Apl[64];            //   512 B  (a, b2) f32
    __shared__ uint32_t Bpl[64];            //   256 B  f16-packed (1+cgb, cbb)
    __shared__ uint8_t  Ll[3][NW];          //   384 B

    int t = threadIdx.x;
    // stage T chunk: 81 rows x 64 u32 (uint4 loads), stride 68 in LDS
    {
        const uint32_t* Tg = T + (size_t)b * 81 * NC + c0;
        int rr = t >> 4, ii = (t & 15) * 4;
        #pragma unroll
        for (int pass = 0; pass < 5; pass++) {
            int r = rr + pass * 16;
            *(uint4*)&Tl[r * TSTRIDE + ii] = *(const uint4*)&Tg[(size_t)r * NC + ii];
        }
        if (t < 16) *(uint4*)&Tl[80 * TSTRIDE + t * 4] = *(const uint4*)&Tg[(size_t)80 * NC + t * 4];
    }
    if (t < 64) { Apl[t] = Ag[c0 + t]; Bpl[t] = Bg[c0 + t]; }
    if (t >= 128 && t < 224) {
        int tt = t - 128;
        int r = tt >> 5, q = tt & 31;
        int hr = h - 1 + r;
        uint32_t v = 0;
        if (hr >= 0 && hr < NH)
            v = ((const uint32_t*)(lab + (size_t)b * NHW + (size_t)hr * NW))[q];
        ((uint32_t*)Ll)[tt] = v;
    }
    __syncthreads();

    int w = t & 127, cg = t >> 7;
    // per-pixel neighbor labels; 8 = OOB (zero row)
    int base_k[9];
    #pragma unroll
    for (int dy = 0; dy < 3; dy++) {
        int hr = h - 1 + dy;
        bool rok = (hr >= 0) && (hr < NH);
        #pragma unroll
        for (int dx = 0; dx < 3; dx++) {
            int ww = w - 1 + dx;
            bool ok = rok && (ww >= 0) && (ww < NW);
            int wc = ww < 0 ? 0 : (ww > NW - 1 ? NW - 1 : ww);
            int j = ok ? (int)Ll[dy][wc] : 8;
            int k = dy * 3 + dx;
            base_k[k] = (k * 9 + j) * TSTRIDE + cg * 32;
        }
    }

    const float* fpb = fp + ((size_t)b * NC + c0 + cg * 32) * NHW + (size_t)h * NW + w;
    float*       ob  = out + ((size_t)b * NC + c0 + cg * 32) * NHW + (size_t)h * NW + w;

    #pragma unroll
    for (int q = 0; q < 8; q++) {
        uint4 bias = *(const uint4*)&Bpl[cg * 32 + q * 4];
        __half2 a0 = u2h(bias.x), a1 = u2h(bias.y), a2 = u2h(bias.z), a3 = u2h(bias.w);
        #pragma unroll
        for (int k = 0; k < 9; k++) {
            uint4 tv = *(const uint4*)&Tl[base_k[k] + q * 4];
            a0 = __hadd2(a0, u2h(tv.x));
            a1 = __hadd2(a1, u2h(tv.y));
            a2 = __hadd2(a2, u2h(tv.z));
            a3 = __hadd2(a3, u2h(tv.w));
        }
        float4 ap01 = *(const float4*)&Apl[cg * 32 + q * 4];
        float4 ap23 = *(const float4*)&Apl[cg * 32 + q * 4 + 2];
        float x0 = fpb[(size_t)(q * 4 + 0) * NHW];
        float x1 = fpb[(size_t)(q * 4 + 1) * NHW];
        float x2 = fpb[(size_t)(q * 4 + 2) * NHW];
        float x3 = fpb[(size_t)(q * 4 + 3) * NHW];
        float2 g0 = __half22float2(a0);
        float2 g1 = __half22float2(a1);
        float2 g2 = __half22float2(a2);
        float2 g3 = __half22float2(a3);
        // non-temporal: don't let `out` write-allocate and evict fp from L3
        __builtin_nontemporal_store((x0 * ap01.x + ap01.y) * g0.x + g0.y, &ob[(size_t)(q * 4 + 0) * NHW]);
        __builtin_nontemporal_store((x1 * ap01.z + ap01.w) * g1.x + g1.y, &ob[(size_t)(q * 4 + 1) * NHW]);
        __builtin_nontemporal_store((x2 * ap23.x + ap23.y) * g2.x + g2.y, &ob[(size_t)(q * 4 + 2) * NHW]);
        __builtin_nontemporal_store((x3 * ap23.z + ap23.w) * g3.x + g3.y, &ob[(size_t)(q * 4 + 3) * NHW]);
    }
}

extern "C" void kernel_launch(void* const* d_in, const int* in_sizes, int n_in,
                              void* d_out, int out_size, void* d_ws, size_t ws_size,
                              hipStream_t stream) {
    const float* fp    = (const float*)d_in[0];
    const float* sg    = (const float*)d_in[1];
    const float* style = (const float*)d_in[2];
    const int*   mask  = (const int*)d_in[3];
    const float* bnw   = (const float*)d_in[4];
    const float* bnb   = (const float*)d_in[5];
    const float* cgw   = (const float*)d_in[6];
    const float* cgb   = (const float*)d_in[7];
    const float* cbw   = (const float*)d_in[8];
    const float* cbb   = (const float*)d_in[9];
    const float* fcw   = (const float*)d_in[10];
    const float* fcb   = (const float*)d_in[11];
    float* out = (float*)d_out;

    char* ws = (char*)d_ws;
    float*    psum = (float*)(ws + 0);           //   8 KB
    float*    psq  = (float*)(ws + 8192);        //   8 KB
    float2*   Al   = (float2*)(ws + 16384);      //   2 KB
    uint32_t* Bl   = (uint32_t*)(ws + 18432);    //   1 KB
    uint8_t*  lab  = (uint8_t*)(ws + 19456);     // 128 KB
    float*    mu   = (float*)(ws + 150528);      //  64 KB
    uint32_t* wpk  = (uint32_t*)(ws + 216064);   // 2.25 MB (f16x2-packed wg,wb)
    uint32_t* T    = (uint32_t*)(ws + 2575360);  // 648 KB  (total ~3.2 MB)

    hipLaunchKernelGGL(kA, dim3(2912), dim3(256), 0, stream,
                       fp, psum, psq, sg, lab, style, mask, fcw, fcb, mu,
                       cgw, cbw, wpk);
    hipLaunchKernelGGL(kB, dim3(73), dim3(1024), 0, stream,
                       psum, psq, bnw, bnb, cgb, cbb, Al, Bl, mu, wpk, T);
    hipLaunchKernelGGL(k_main, dim3(NB * NH * 4), dim3(256), 0, stream,
                       fp, lab, T, Al, Bl, out);
}

// Round 6
// 85.021 us; speedup vs baseline: 1.9740x; 1.0649x over previous
//
#include <hip/hip_runtime.h>
#include <hip/hip_fp16.h>
#include <stdint.h>

#define NB 8
#define NC 256
#define NH 128
#define NW 128
#define NJ 8
#define NS 256
#define NHW (NH*NW)   // 16384
#define BN_EPS 1e-5f
#define TSTRIDE 68    // u32 stride per (k,j) row in LDS: 16B-aligned, 4j%32 banks

__device__ inline __half2 u2h(uint32_t u) {
    union { uint32_t u; __half2 h; } x; x.u = u; return x.h;
}
__device__ inline uint32_t h2u(__half2 h) {
    union { uint32_t u; __half2 h; } x; x.h = h; return x.u;
}

// ============ Kernel A: labels | mu | transpose+pack | stats ============
// blocks [0,512): label map
// blocks [512,576): mu (64 = b*8+j)
// blocks [576,864): weight transpose+f16-pack
// blocks [864,2912): BN partial sums (bulk last: small parts overlap ramp)
__global__ __launch_bounds__(256) void kA(
        const float* __restrict__ fp, float* __restrict__ psum, float* __restrict__ psq,
        const float* __restrict__ sg, uint8_t* __restrict__ lab,
        const float* __restrict__ style, const int* __restrict__ mask,
        const float* __restrict__ fcw, const float* __restrict__ fcb,
        float* __restrict__ mu,
        const float* __restrict__ wg, const float* __restrict__ wb,
        uint32_t* __restrict__ wpk) {
    __shared__ float ls[4], lq[4];
    __shared__ float code[NS];
    __shared__ uint32_t tileu[32][65];
    int blk = blockIdx.x;
    int t = threadIdx.x;
    if (blk < 512) {
        // ---- labels: one-hot argmax ----
        int pix = blk * 256 + t;
        int b = pix >> 14, hw = pix & 16383;
        const float* base = sg + (size_t)b * NJ * NHW + hw;
        int l = 0;
        #pragma unroll
        for (int j = 0; j < NJ; j++)
            if (base[(size_t)j * NHW] > 0.5f) l = j;
        lab[pix] = (uint8_t)l;
    } else if (blk < 576) {
        // ---- mu[b,j,t] = relu(fc_j(code)) ----
        int bj = blk - 512;
        int b = bj >> 3, j = bj & 7;
        int row = (mask[bj] == 1) ? j : NJ;
        code[t] = style[((size_t)b * (NJ + 1) + row) * NS + t];
        __syncthreads();
        const float4* w4 = (const float4*)(fcw + ((size_t)j * NS + t) * NS);
        const float4* c4 = (const float4*)code;
        float acc = fcb[j * NS + t];
        for (int s4 = 0; s4 < NS / 4; s4++) {
            float4 wv = w4[s4];
            float4 cv = c4[s4];
            acc += wv.x * cv.x + wv.y * cv.y + wv.z * cv.z + wv.w * cv.w;
        }
        mu[bj * NS + t] = fmaxf(acc, 0.f);
    } else if (blk < 864) {
        // ---- transpose+pack [c][sk]x2 -> wpk[k][s][c] u32(h2: wg,wb) ----
        int i = blk - 576;                     // 0..287
        int skc = i % 72, cc = i / 72;
        int sk0 = skc * 32, c0 = cc * 64;
        {
            int skl = t & 31, cl = t >> 5;     // 8 c per pass
            #pragma unroll
            for (int p = 0; p < 8; p++) {
                int c = c0 + cl + p * 8;
                float g  = __builtin_nontemporal_load(&wg[(size_t)c * 2304 + sk0 + skl]);
                float b2 = __builtin_nontemporal_load(&wb[(size_t)c * 2304 + sk0 + skl]);
                tileu[skl][cl + p * 8] = h2u(__floats2half2_rn(g, b2));
            }
        }
        __syncthreads();
        {
            int cl = t & 63, skl = t >> 6;     // 4 sk per pass
            #pragma unroll
            for (int p = 0; p < 8; p++) {
                int sk = sk0 + skl + p * 4;
                int s = sk / 9, k = sk - s * 9;
                wpk[(size_t)k * (NS * NC) + (size_t)s * NC + c0 + cl] = tileu[skl + p * 4][cl];
            }
        }
    } else {
        // ---- BN stats over one (b,c) plane ----
        int bc = blk - 864;
        int b = bc >> 8, c = bc & 255;
        const float4* p = (const float4*)(fp + (size_t)(b * NC + c) * NHW);
        float s = 0.f, q = 0.f;
        for (int i = t; i < NHW / 4; i += 256) {
            float4 v = p[i];
            s += v.x + v.y + v.z + v.w;
            q += v.x * v.x + v.y * v.y + v.z * v.z + v.w * v.w;
        }
        for (int o = 32; o > 0; o >>= 1) {
            s += __shfl_down(s, o);
            q += __shfl_down(q, o);
        }
        int wid = t >> 6, lane = t & 63;
        if (lane == 0) { ls[wid] = s; lq[wid] = q; }
        __syncthreads();
        if (t == 0) {
            float S2 = 0.f, Q2 = 0.f;
            for (int i = 0; i < 4; i++) { S2 += ls[i]; Q2 += lq[i]; }
            psum[c * 8 + b] = S2;
            psq[c * 8 + b] = Q2;
        }
    }
}

// ============ Kernel B: tables (blk 0..71) | params (blk 72) ============
// tables: 1024 thr = 256 c x 4 j-pairs; mu staged [s][j] in LDS
__global__ __launch_bounds__(1024) void kB(
        const float* __restrict__ psum, const float* __restrict__ psq,
        const float* __restrict__ bnw, const float* __restrict__ bnb,
        const float* __restrict__ cgb, const float* __restrict__ cbb,
        float2* __restrict__ Al, uint32_t* __restrict__ Bl,
        const float* __restrict__ mu, const uint32_t* __restrict__ wpk,
        uint32_t* __restrict__ T) {
    int blk = blockIdx.x;
    int t = threadIdx.x;
    if (blk == 72) {
        if (t < 256) {
            int c = t;
            float s = 0.f, q = 0.f;
            for (int b = 0; b < NB; b++) { s += psum[c * 8 + b]; q += psq[c * 8 + b]; }
            const float N = (float)(NB * NHW);
            float mean = s / N;
            float var = q / N - mean * mean;
            if (var < 0.f) var = 0.f;
            float inv = 1.0f / sqrtf(var + BN_EPS);
            float a = bnw[c] * inv;
            float b2 = bnb[c] - mean * a;
            Al[c] = make_float2(a, b2);
            Bl[c] = h2u(__floats2half2_rn(1.0f + cgb[c], cbb[c]));  // (G0, B0)
        }
        return;
    }
    int b = blk / 9, k = blk - b * 9;
    __shared__ float ms[NS * NJ];   // [s][j] layout
    for (int i = t; i < NJ * NS; i += 1024) {
        int j = i >> 8, s = i & 255;
        ms[s * 8 + j] = mu[(size_t)b * NJ * NS + i];
    }
    __syncthreads();
    int c = t & 255, jq = t >> 8;
    int j0 = jq * 2;
    const uint32_t* wp = wpk + (size_t)k * NS * NC + c;
    float g0 = 0.f, be0 = 0.f, g1 = 0.f, be1 = 0.f;
    for (int s = 0; s < NS; s++) {
        float2 w2 = __half22float2(u2h(wp[(size_t)s * NC]));
        float2 mm = *(const float2*)&ms[s * 8 + j0];
        g0  += mm.x * w2.x;  be0 += mm.x * w2.y;
        g1  += mm.y * w2.x;  be1 += mm.y * w2.y;
    }
    uint32_t* o = T + ((size_t)b * 9 + k) * 9 * NC + c;
    o[(size_t)j0 * NC]       = h2u(__floats2half2_rn(g0, be0));
    o[(size_t)(j0 + 1) * NC] = h2u(__floats2half2_rn(g1, be1));
    if (jq == 0) o[(size_t)8 * NC] = 0u;   // zero row for OOB neighbors
}

// tree-accumulate one 32-bit lane-word (two f16) across 9 taps + bias
#define TAP_TREE(FLD, OUT)                                              \
    {                                                                   \
        __half2 p01 = __hadd2(u2h(tv[0].FLD), u2h(tv[1].FLD));          \
        __half2 p23 = __hadd2(u2h(tv[2].FLD), u2h(tv[3].FLD));          \
        __half2 p45 = __hadd2(u2h(tv[4].FLD), u2h(tv[5].FLD));          \
        __half2 p67 = __hadd2(u2h(tv[6].FLD), u2h(tv[7].FLD));          \
        __half2 p8b = __hadd2(u2h(tv[8].FLD), u2h(bias.FLD));           \
        OUT = __hadd2(__hadd2(__hadd2(p01, p23), __hadd2(p45, p67)), p8b); \
    }

// ============ Kernel C: fused BN + table-gather "conv" + modulation ======
// grid: b(8) x h(128) x cchunk(4, 64 channels each); 256 thr = 128 w x 2 cg
__global__ __launch_bounds__(256, 5) void k_main(
        const float* __restrict__ fp, const uint8_t* __restrict__ lab,
        const uint32_t* __restrict__ T, const float2* __restrict__ Ag,
        const uint32_t* __restrict__ Bg, float* __restrict__ out) {
    int blk = blockIdx.x;
    int cc = blk & 3;
    int h  = (blk >> 2) & 127;
    int b  = blk >> 9;
    int c0 = cc * 64;

    __shared__ uint32_t Tl[81 * TSTRIDE];   // 22032 B
    __shared__ float2   Apl[64];            //   512 B  (a, b2) f32
    __shared__ uint32_t Bpl[64];            //   256 B  f16-packed (1+cgb, cbb)
    __shared__ uint8_t  Ll[3][NW];          //   384 B

    int t = threadIdx.x;
    // stage T chunk: 81 rows x 64 u32 (uint4 loads), stride 68 in LDS
    {
        const uint32_t* Tg = T + (size_t)b * 81 * NC + c0;
        int rr = t >> 4, ii = (t & 15) * 4;
        #pragma unroll
        for (int pass = 0; pass < 5; pass++) {
            int r = rr + pass * 16;
            *(uint4*)&Tl[r * TSTRIDE + ii] = *(const uint4*)&Tg[(size_t)r * NC + ii];
        }
        if (t < 16) *(uint4*)&Tl[80 * TSTRIDE + t * 4] = *(const uint4*)&Tg[(size_t)80 * NC + t * 4];
    }
    if (t < 64) { Apl[t] = Ag[c0 + t]; Bpl[t] = Bg[c0 + t]; }
    if (t >= 128 && t < 224) {
        int tt = t - 128;
        int r = tt >> 5, q = tt & 31;
        int hr = h - 1 + r;
        uint32_t v = 0;
        if (hr >= 0 && hr < NH)
            v = ((const uint32_t*)(lab + (size_t)b * NHW + (size_t)hr * NW))[q];
        ((uint32_t*)Ll)[tt] = v;
    }
    __syncthreads();

    int w = t & 127, cg = t >> 7;
    // per-pixel neighbor labels; 8 = OOB (zero row)
    int base_k[9];
    #pragma unroll
    for (int dy = 0; dy < 3; dy++) {
        int hr = h - 1 + dy;
        bool rok = (hr >= 0) && (hr < NH);
        #pragma unroll
        for (int dx = 0; dx < 3; dx++) {
            int ww = w - 1 + dx;
            bool ok = rok && (ww >= 0) && (ww < NW);
            int wc = ww < 0 ? 0 : (ww > NW - 1 ? NW - 1 : ww);
            int j = ok ? (int)Ll[dy][wc] : 8;
            int k = dy * 3 + dx;
            base_k[k] = (k * 9 + j) * TSTRIDE + cg * 32;
        }
    }

    const float* fpb = fp + ((size_t)b * NC + c0 + cg * 32) * NHW + (size_t)h * NW + w;
    float*       ob  = out + ((size_t)b * NC + c0 + cg * 32) * NHW + (size_t)h * NW + w;

    #pragma unroll
    for (int q = 0; q < 8; q++) {
        // global loads first: latency hides under the gather tree
        float x0 = fpb[(size_t)(q * 4 + 0) * NHW];
        float x1 = fpb[(size_t)(q * 4 + 1) * NHW];
        float x2 = fpb[(size_t)(q * 4 + 2) * NHW];
        float x3 = fpb[(size_t)(q * 4 + 3) * NHW];
        // all 9 taps issued independently (static indices -> registers)
        uint4 tv[9];
        #pragma unroll
        for (int k = 0; k < 9; k++)
            tv[k] = *(const uint4*)&Tl[base_k[k] + q * 4];
        uint4 bias = *(const uint4*)&Bpl[cg * 32 + q * 4];
        __half2 a0, a1, a2, a3;
        TAP_TREE(x, a0);
        TAP_TREE(y, a1);
        TAP_TREE(z, a2);
        TAP_TREE(w, a3);
        float4 ap01 = *(const float4*)&Apl[cg * 32 + q * 4];
        float4 ap23 = *(const float4*)&Apl[cg * 32 + q * 4 + 2];
        float2 g0 = __half22float2(a0);
        float2 g1 = __half22float2(a1);
        float2 g2 = __half22float2(a2);
        float2 g3 = __half22float2(a3);
        // non-temporal: don't let `out` write-allocate and evict fp from L3
        __builtin_nontemporal_store((x0 * ap01.x + ap01.y) * g0.x + g0.y, &ob[(size_t)(q * 4 + 0) * NHW]);
        __builtin_nontemporal_store((x1 * ap01.z + ap01.w) * g1.x + g1.y, &ob[(size_t)(q * 4 + 1) * NHW]);
        __builtin_nontemporal_store((x2 * ap23.x + ap23.y) * g2.x + g2.y, &ob[(size_t)(q * 4 + 2) * NHW]);
        __builtin_nontemporal_store((x3 * ap23.z + ap23.w) * g3.x + g3.y, &ob[(size_t)(q * 4 + 3) * NHW]);
    }
}

extern "C" void kernel_launch(void* const* d_in, const int* in_sizes, int n_in,
                              void* d_out, int out_size, void* d_ws, size_t ws_size,
                              hipStream_t stream) {
    const float* fp    = (const float*)d_in[0];
    const float* sg    = (const float*)d_in[1];
    const float* style = (const float*)d_in[2];
    const int*   mask  = (const int*)d_in[3];
    const float* bnw   = (const float*)d_in[4];
    const float* bnb   = (const float*)d_in[5];
    const float* cgw   = (const float*)d_in[6];
    const float* cgb   = (const float*)d_in[7];
    const float* cbw   = (const float*)d_in[8];
    const float* cbb   = (const float*)d_in[9];
    const float* fcw   = (const float*)d_in[10];
    const float* fcb   = (const float*)d_in[11];
    float* out = (float*)d_out;

    char* ws = (char*)d_ws;
    float*    psum = (float*)(ws + 0);           //   8 KB
    float*    psq  = (float*)(ws + 8192);        //   8 KB
    float2*   Al   = (float2*)(ws + 16384);      //   2 KB
    uint32_t* Bl   = (uint32_t*)(ws + 18432);    //   1 KB
    uint8_t*  lab  = (uint8_t*)(ws + 19456);     // 128 KB
    float*    mu   = (float*)(ws + 150528);      //  64 KB
    uint32_t* wpk  = (uint32_t*)(ws + 216064);   // 2.25 MB (f16x2-packed wg,wb)
    uint32_t* T    = (uint32_t*)(ws + 2575360);  // 648 KB  (total ~3.2 MB)

    hipLaunchKernelGGL(kA, dim3(2912), dim3(256), 0, stream,
                       fp, psum, psq, sg, lab, style, mask, fcw, fcb, mu,
                       cgw, cbw, wpk);
    hipLaunchKernelGGL(kB, dim3(73), dim3(1024), 0, stream,
                       psum, psq, bnw, bnb, cgb, cbb, Al, Bl, mu, wpk, T);
    hipLaunchKernelGGL(k_main, dim3(NB * NH * 4), dim3(256), 0, stream,
                       fp, lab, T, Al, Bl, out);
}